// Round 3
// baseline (113.742 us; speedup 1.0000x reference)
//
#include <hip/hip_runtime.h>
#include <math.h>

// Problem constants (reference: B=4, N=M=8192, D=3, fp32)
#define BQ     4
#define NPTS   8192
#define WG     256
#define CHUNK  512                // m-points staged in LDS per block
#define UA     8                  // a-points per thread (registers)
#define ABLK   (WG * UA)          // 2048 a-points per block
#define NCH    (NPTS / CHUNK)     // 16 m-chunks
#define TOTALA (2 * BQ * NPTS)    // 65536 a-points across batch*dir

// Per (a-chunk, m-chunk, batch*dir): min over the m-chunk of
//   d^2 = ||a||^2 + (||b||^2 - 2 a.b)
// b' = (-2bx, -2by, -2bz, ||b||^2) staged in LDS; inner update is
// 3 fma per m-point + fused v_min3 over m-pairs. UA=8 keeps the
// 2 ds_read_b128 per m-pair below VALU issue demand.
__global__ __launch_bounds__(WG) void chamfer_min_kernel(
    const float* __restrict__ yhat, const float* __restrict__ y,
    unsigned* __restrict__ part, float* __restrict__ scratch, int atomicPath) {
  // zero the fused-reduce accumulator+counter once per launch
  if (blockIdx.x == 0 && blockIdx.y == 0 && blockIdx.z == 0 && threadIdx.x == 0) {
    scratch[0] = 0.f;
    ((unsigned*)scratch)[1] = 0u;
  }

  const int bz = blockIdx.z, b = bz >> 1, dir = bz & 1;
  const float* A  = (dir ? y    : yhat) + (size_t)b * NPTS * 3;
  const float* Bp = (dir ? yhat : y   ) + (size_t)b * NPTS * 3;

  __shared__ float4 bs[CHUNK];
  const int m0 = blockIdx.y * CHUNK;
  for (int i = threadIdx.x; i < CHUNK; i += WG) {
    const float* p = Bp + (size_t)(m0 + i) * 3;
    const float x = p[0], yv = p[1], z = p[2];
    bs[i] = make_float4(-2.f * x, -2.f * yv, -2.f * z,
                        fmaf(x, x, fmaf(yv, yv, z * z)));
  }

  const int nbase = blockIdx.x * ABLK + threadIdx.x;
  float ax[UA], ay[UA], az[UA], mn[UA];
#pragma unroll
  for (int k = 0; k < UA; ++k) {
    const float* p = A + (size_t)(nbase + k * WG) * 3;
    ax[k] = p[0]; ay[k] = p[1]; az[k] = p[2];
    mn[k] = 3.0e38f;
  }
  __syncthreads();

#pragma unroll 2
  for (int m = 0; m < CHUNK; m += 2) {
    const float4 b0 = bs[m], b1 = bs[m + 1];
#pragma unroll
    for (int k = 0; k < UA; ++k) {
      const float t0 = fmaf(ax[k], b0.x, fmaf(ay[k], b0.y, fmaf(az[k], b0.z, b0.w)));
      const float t1 = fmaf(ax[k], b1.x, fmaf(ay[k], b1.y, fmaf(az[k], b1.z, b1.w)));
      mn[k] = fminf(mn[k], fminf(t0, t1));  // v_min3_f32
    }
  }

  const int base = bz * NPTS + blockIdx.x * ABLK + threadIdx.x;
  if (atomicPath) {
#pragma unroll
    for (int k = 0; k < UA; ++k) {
      const float sq = fmaf(ax[k], ax[k], fmaf(ay[k], ay[k], az[k] * az[k]));
      const float d2 = fmaxf(sq + mn[k], 0.f);
      atomicMin(&part[base + k * WG], __float_as_uint(d2));
    }
  } else {
    unsigned* outp = part + (size_t)blockIdx.y * TOTALA;
#pragma unroll
    for (int k = 0; k < UA; ++k) {
      const float sq = fmaf(ax[k], ax[k], fmaf(ay[k], ay[k], az[k] * az[k]));
      const float d2 = fmaxf(sq + mn[k], 0.f);
      outp[base + k * WG] = __float_as_uint(d2);
    }
  }
}

// Fused: min across m-chunks -> block sums -> atomicAdd -> last block sqrt+store.
__global__ __launch_bounds__(256) void chamfer_reduce_final_kernel(
    const unsigned* __restrict__ part, float* __restrict__ scratch,
    float* __restrict__ out, int nch) {
  const int gid = blockIdx.x * 256 + threadIdx.x;  // 64 blocks -> 0..16383
  float s = 0.f;
#pragma unroll
  for (int rep = 0; rep < TOTALA / (64 * 256); ++rep) {
    const int j = rep * 16384 + gid;
    float mv = __uint_as_float(part[j]);
    for (int mc = 1; mc < nch; ++mc)
      mv = fminf(mv, __uint_as_float(part[(size_t)mc * TOTALA + j]));
    s += mv;
  }
#pragma unroll
  for (int off = 32; off > 0; off >>= 1) s += __shfl_down(s, off, 64);
  __shared__ float p4[4];
  const int wave = threadIdx.x >> 6, lane = threadIdx.x & 63;
  if (lane == 0) p4[wave] = s;
  __syncthreads();
  if (threadIdx.x == 0) {
    atomicAdd(&scratch[0], p4[0] + p4[1] + p4[2] + p4[3]);
    __threadfence();
    const unsigned ticket = atomicAdd(&((unsigned*)scratch)[1], 1u);
    if (ticket == gridDim.x - 1) {
      __threadfence();
      const float total = atomicAdd(&scratch[0], 0.f);  // atomic read
      out[0] = sqrtf(total * (1.0f / (float)TOTALA));
    }
  }
}

extern "C" void kernel_launch(void* const* d_in, const int* in_sizes, int n_in,
                              void* d_out, int out_size, void* d_ws, size_t ws_size,
                              hipStream_t stream) {
  const float* yhat = (const float*)d_in[0];
  const float* y    = (const float*)d_in[1];
  unsigned* part = (unsigned*)d_ws;

  const size_t needFull = ((size_t)NCH * TOTALA + 2) * sizeof(unsigned);
  const int atomicPath = ws_size < needFull;

  float* scratch;
  if (atomicPath) {
    // init to +big so atomicMin on float bits works (all d2 >= 0)
    hipMemsetAsync(part, 0x7F, (size_t)TOTALA * sizeof(unsigned), stream);
    scratch = (float*)(part + TOTALA);
  } else {
    scratch = (float*)(part + (size_t)NCH * TOTALA);
  }

  dim3 grid(NPTS / ABLK, NCH, 2 * BQ);
  chamfer_min_kernel<<<grid, WG, 0, stream>>>(yhat, y, part, scratch, atomicPath);
  chamfer_reduce_final_kernel<<<64, 256, 0, stream>>>(part, scratch, (float*)d_out,
                                                      atomicPath ? 1 : NCH);
}

// Round 5
// 107.024 us; speedup vs baseline: 1.0628x; 1.0628x over previous
//
#include <hip/hip_runtime.h>
#include <math.h>

// Problem constants (reference: B=4, N=M=8192, D=3, fp32)
#define BQ     4
#define NPTS   8192
#define WG     256
#define CHUNK  512                // m-points staged in LDS per block
#define UA     8                  // a-points per thread (registers)
#define ABLK   (WG * UA)          // 2048 a-points per block
#define NCH    (NPTS / CHUNK)     // 16 m-chunks
#define TOTALA (2 * BQ * NPTS)    // 65536 a-points across batch*dir

// Per (a-chunk, m-chunk, batch*dir): min over the m-chunk of
//   d^2 = ||a||^2 + (||b||^2 - 2 a.b)
// b' = (-2bx, -2by, -2bz, ||b||^2) staged in LDS; inner update is
// 3 fma per m-point + fused v_min3 over m-pairs.
// __launch_bounds__(WG,2): 2 waves/EU is all we need -> VGPR budget up to
// ~256 so ax/ay/az/mn (32 regs) + b0/b1 + temps stay register-resident and
// the LDS read stays at 2 ds_read_b128 per m-pair.
__global__ __launch_bounds__(WG, 2) void chamfer_min_kernel(
    const float* __restrict__ yhat, const float* __restrict__ y,
    unsigned* __restrict__ part, float* __restrict__ scratch, int atomicPath) {
  // zero the fused-reduce accumulator+counter once (safe: no other block in
  // THIS kernel touches scratch; consumers run in the next kernel)
  if (blockIdx.x == 0 && blockIdx.y == 0 && blockIdx.z == 0 && threadIdx.x == 0) {
    scratch[0] = 0.f;
    ((unsigned*)scratch)[1] = 0u;
  }

  const int bz = blockIdx.z, b = bz >> 1, dir = bz & 1;
  const float* A  = (dir ? y    : yhat) + (size_t)b * NPTS * 3;
  const float* Bp = (dir ? yhat : y   ) + (size_t)b * NPTS * 3;

  __shared__ float4 bs[CHUNK];
  const int m0 = blockIdx.y * CHUNK;
  for (int i = threadIdx.x; i < CHUNK; i += WG) {
    const float* p = Bp + (size_t)(m0 + i) * 3;
    const float x = p[0], yv = p[1], z = p[2];
    bs[i] = make_float4(-2.f * x, -2.f * yv, -2.f * z,
                        fmaf(x, x, fmaf(yv, yv, z * z)));
  }

  const int nbase = blockIdx.x * ABLK + threadIdx.x;
  float ax[UA], ay[UA], az[UA], mn[UA];
#pragma unroll
  for (int k = 0; k < UA; ++k) {
    const float* p = A + (size_t)(nbase + k * WG) * 3;
    ax[k] = p[0]; ay[k] = p[1]; az[k] = p[2];
    mn[k] = 3.0e38f;
  }
  __syncthreads();

  for (int m = 0; m < CHUNK; m += 2) {
    const float4 b0 = bs[m], b1 = bs[m + 1];
#pragma unroll
    for (int k = 0; k < UA; ++k) {
      const float t0 = fmaf(ax[k], b0.x, fmaf(ay[k], b0.y, fmaf(az[k], b0.z, b0.w)));
      const float t1 = fmaf(ax[k], b1.x, fmaf(ay[k], b1.y, fmaf(az[k], b1.z, b1.w)));
      mn[k] = fminf(mn[k], fminf(t0, t1));  // v_min3_f32
    }
  }

  const int base = bz * NPTS + blockIdx.x * ABLK + threadIdx.x;
  if (atomicPath) {
#pragma unroll
    for (int k = 0; k < UA; ++k) {
      const float sq = fmaf(ax[k], ax[k], fmaf(ay[k], ay[k], az[k] * az[k]));
      const float d2 = fmaxf(sq + mn[k], 0.f);
      atomicMin(&part[base + k * WG], __float_as_uint(d2));
    }
  } else {
    unsigned* outp = part + (size_t)blockIdx.y * TOTALA;
#pragma unroll
    for (int k = 0; k < UA; ++k) {
      const float sq = fmaf(ax[k], ax[k], fmaf(ay[k], ay[k], az[k] * az[k]));
      const float d2 = fmaxf(sq + mn[k], 0.f);
      outp[base + k * WG] = __float_as_uint(d2);
    }
  }
}

// One j per thread; min across chunks with per-WAVE rotated chunk order
// (full coalescing within a wave, spreads the 256 KB power-of-2 stride
// across channels); then sum -> atomicAdd -> last block does sqrt+store.
__global__ __launch_bounds__(256) void chamfer_reduce_final_kernel(
    const unsigned* __restrict__ part, float* __restrict__ scratch,
    float* __restrict__ out, int nch) {
  const int j = blockIdx.x * 256 + threadIdx.x;  // 256 blocks -> 0..65535
  const int wave = threadIdx.x >> 6, lane = threadIdx.x & 63;
  const int rot = (blockIdx.x * 4 + wave) & (NCH - 1);
  float mv = 3.4e38f;
  if (nch == 1) {
    mv = __uint_as_float(part[j]);
  } else {
#pragma unroll
    for (int c = 0; c < NCH; ++c) {
      const int mc = (c + rot) & (NCH - 1);
      mv = fminf(mv, __uint_as_float(part[(size_t)mc * TOTALA + j]));
    }
  }
  float s = mv;
#pragma unroll
  for (int off = 32; off > 0; off >>= 1) s += __shfl_down(s, off, 64);
  __shared__ float p4[4];
  if (lane == 0) p4[wave] = s;
  __syncthreads();
  if (threadIdx.x == 0) {
    atomicAdd(&scratch[0], p4[0] + p4[1] + p4[2] + p4[3]);
    __threadfence();
    const unsigned ticket = atomicAdd(&((unsigned*)scratch)[1], 1u);
    if (ticket == gridDim.x - 1) {
      __threadfence();
      const float total = atomicAdd(&scratch[0], 0.f);  // atomic read
      out[0] = sqrtf(total * (1.0f / (float)TOTALA));
    }
  }
}

extern "C" void kernel_launch(void* const* d_in, const int* in_sizes, int n_in,
                              void* d_out, int out_size, void* d_ws, size_t ws_size,
                              hipStream_t stream) {
  const float* yhat = (const float*)d_in[0];
  const float* y    = (const float*)d_in[1];
  unsigned* part = (unsigned*)d_ws;

  const size_t needFull = ((size_t)NCH * TOTALA + 2) * sizeof(unsigned);
  const int atomicPath = ws_size < needFull;

  float* scratch;
  if (atomicPath) {
    // init to +big so atomicMin on float bits works (all d2 >= 0)
    hipMemsetAsync(part, 0x7F, (size_t)TOTALA * sizeof(unsigned), stream);
    scratch = (float*)(part + TOTALA);
  } else {
    scratch = (float*)(part + (size_t)NCH * TOTALA);
  }

  dim3 grid(NPTS / ABLK, NCH, 2 * BQ);
  chamfer_min_kernel<<<grid, WG, 0, stream>>>(yhat, y, part, scratch, atomicPath);
  chamfer_reduce_final_kernel<<<256, 256, 0, stream>>>(part, scratch, (float*)d_out,
                                                       atomicPath ? 1 : NCH);
}